// Round 10
// baseline (129.391 us; speedup 1.0000x reference)
//
#include <hip/hip_runtime.h>

typedef unsigned short u16;
typedef float f32x4 __attribute__((ext_vector_type(4)));
typedef __bf16 bf16x8 __attribute__((ext_vector_type(8)));
typedef unsigned int u32x4 __attribute__((ext_vector_type(4)));
typedef u16 u16x4 __attribute__((ext_vector_type(4)));
typedef u16 u16x8 __attribute__((ext_vector_type(8)));

static __device__ __forceinline__ u16 f2bf(float f) {
  union { __bf16 h; u16 u; } c;
  c.h = (__bf16)f;
  return c.u;
}

static __device__ __forceinline__ void gload_lds16(const void* g, void* l) {
  __builtin_amdgcn_global_load_lds(
      (const __attribute__((address_space(1))) unsigned int*)g,
      (__attribute__((address_space(3))) unsigned int*)l, 16, 0, 0);
}

// ---------------- fused fp32 -> bf16 convert (x, Wqkv, Wproj in one launch) ----------------
__global__ __launch_bounds__(256) void cvt3_f32_bf16(const float* __restrict__ a,
                                                     const float* __restrict__ bb,
                                                     const float* __restrict__ cc,
                                                     u16* __restrict__ out,
                                                     int n1, int n2, int n3) {
  int i = blockIdx.x * 256 + threadIdx.x;
  const float* src;
  int j = i;
  if (i < n1) { src = a; }
  else if (i < n1 + n2) { src = bb; j = i - n1; }
  else { src = cc; j = i - n1 - n2; if (j >= n3) return; }
  f32x4 v = *((const f32x4*)src + j);
  u16x4 o;
  o[0] = f2bf(v[0]); o[1] = f2bf(v[1]); o[2] = f2bf(v[2]); o[3] = f2bf(v[3]);
  *((u16x4*)out + i) = o;
}

// ---------------- GEMM: C[M,N] = A[M,K] * B[N,K]^T (bf16 in, fp32 acc) ----------------
// 128x128 tile, BK=64, 4 waves. global_load_lds w16 staging, both-sides swizzle.
// XCD-aware 1D decode. FUSE_VT: v-panels (bn>=2048) write vt[bh][d][t] directly
// (transposed, packed u16x4 over 4 consecutive t) and skip the qkv v-write.
template<int OUT_BF16, int FUSE_VT>
__global__ __launch_bounds__(256) void gemm_nt(const u16* __restrict__ A,
                                               const u16* __restrict__ B,
                                               void* __restrict__ Cp,
                                               u16* __restrict__ vt,
                                               int M, int N, int K, int gy) {
  __shared__ __align__(16) u16 lA[128 * 64];
  __shared__ __align__(16) u16 lB[128 * 64];
  const int tid = threadIdx.x;
  const int lane = tid & 63;
  const int wave = tid >> 6;
  const int wm = wave >> 1, wn = wave & 1;
  const int l15 = lane & 15, lg = lane >> 4;

  const int bid = blockIdx.x;
  const int xcd = bid & 7, s = bid >> 3;
  const int pnx = (N >> 7) >> 3;            // B-panels per XCD
  const int bm = (s % gy) * 128;
  const int bn = (xcd * pnx + s / gy) * 128;

  f32x4 acc[4][4];
#pragma unroll
  for (int i = 0; i < 4; ++i)
#pragma unroll
    for (int j = 0; j < 4; ++j) acc[i][j] = (f32x4){0.f, 0.f, 0.f, 0.f};

  const u16* Ag[4];
  const u16* Bg[4];
#pragma unroll
  for (int it = 0; it < 4; ++it) {
    const int ss = it * 256 + tid;
    const int row = ss >> 3, g = ss & 7;
    const int gsw = g ^ (row & 7);  // inverse swizzle on global source
    Ag[it] = A + (size_t)(bm + row) * K + gsw * 8;
    Bg[it] = B + (size_t)(bn + row) * K + gsw * 8;
  }

  for (int k0 = 0; k0 < K; k0 += 64) {
#pragma unroll
    for (int it = 0; it < 4; ++it) {
      gload_lds16(Ag[it] + k0, (u16*)lA + (size_t)(it * 256 + tid) * 8);
      gload_lds16(Bg[it] + k0, (u16*)lB + (size_t)(it * 256 + tid) * 8);
    }
    __syncthreads();
#pragma unroll
    for (int kk = 0; kk < 2; ++kk) {
      bf16x8 af[4], bfv[4];
#pragma unroll
      for (int mf = 0; mf < 4; ++mf) {
        const int row = wm * 64 + mf * 16 + l15;
        af[mf] = *(const bf16x8*)((const char*)lA + row * 128 +
                                  ((kk * 64 + lg * 16) ^ ((row & 7) << 4)));
      }
#pragma unroll
      for (int nf = 0; nf < 4; ++nf) {
        const int row = wn * 64 + nf * 16 + l15;
        bfv[nf] = *(const bf16x8*)((const char*)lB + row * 128 +
                                   ((kk * 64 + lg * 16) ^ ((row & 7) << 4)));
      }
#pragma unroll
      for (int mf = 0; mf < 4; ++mf)
#pragma unroll
        for (int nf = 0; nf < 4; ++nf)
          acc[mf][nf] = __builtin_amdgcn_mfma_f32_16x16x32_bf16(af[mf], bfv[nf], acc[mf][nf], 0, 0, 0);
    }
    __syncthreads();
  }

  if (FUSE_VT && bn >= 2048) {
    // v-panel: write vt[bh][d][t] transposed; rows r are 4 consecutive t.
#pragma unroll
    for (int mf = 0; mf < 4; ++mf) {
      const int row0 = bm + wm * 64 + mf * 16 + lg * 4;
      const int b = row0 >> 11, t0 = row0 & 2047;
#pragma unroll
      for (int nf = 0; nf < 4; ++nf) {
        const int colv = bn - 2048 + wn * 64 + nf * 16 + l15;
        const int h = colv >> 6, d = colv & 63;
        u16x4 pk;
        pk[0] = f2bf(acc[mf][nf][0]); pk[1] = f2bf(acc[mf][nf][1]);
        pk[2] = f2bf(acc[mf][nf][2]); pk[3] = f2bf(acc[mf][nf][3]);
        *(u16x4*)&vt[((size_t)((b * 16 + h) * 64 + d)) * 2048 + t0] = pk;
      }
    }
  } else {
#pragma unroll
    for (int mf = 0; mf < 4; ++mf) {
#pragma unroll
      for (int r = 0; r < 4; ++r) {
        const int row = bm + wm * 64 + mf * 16 + lg * 4 + r;
#pragma unroll
        for (int nf = 0; nf < 4; ++nf) {
          const int col = bn + wn * 64 + nf * 16 + l15;
          const float v = acc[mf][nf][r];
          if (OUT_BF16) ((u16*)Cp)[(size_t)row * N + col] = f2bf(v);
          else          ((float*)Cp)[(size_t)row * N + col] = v;
        }
      }
    }
  }
}

// ---------------- flash attention fwd (causal), bf16 MFMA, KVBLK=128 ----------------
// Paired q-tiles (pi, 31-pi): exactly 17 kv-iters/block for all pi. dbuf K/V
// (1 barrier/iter), 2-deep prefetch, XCD-aware decode. Swapped QK^T (lane owns
// one q-row; 32 kv values in regs): in-register tree + 2 shfl_xor. THR=0
// defer-max (exact). Per-wave P region, no P barrier.
__global__ __launch_bounds__(256) void attn_fwd(const u16* __restrict__ qkv,
                                                const u16* __restrict__ vt,
                                                u16* __restrict__ y) {
  constexpr int T = 2048, C = 1024, C3 = 3072, D = 64, NQ = 32, KB = 128;
  __shared__ __align__(16) u16 lK[2][KB * 64];   // [kv 128][d 64], 128B rows, swz (row&7)<<4
  __shared__ __align__(16) u16 lV[2][64 * KB];   // [d 64][kv 128], 256B rows, swz (d&15)<<4
  __shared__ __align__(16) u16 lP[4 * 16 * KB];  // per-wave [q 16][kv 128], swz (q&15)<<4
  const int tid = threadIdx.x, lane = tid & 63, w = tid >> 6;
  const int l15 = lane & 15, lg = lane >> 4;

  const int bid = blockIdx.x;
  const int xcd = bid & 7, slot = bid >> 3;
  const int bh = xcd * 4 + (slot >> 4);
  const int pi = slot & 15;
  const int b = bh >> 4, h = bh & 15;

  // staging maps: 4 chunks of 16B per thread per tile, for K and V
  int kr[4], ko[4], ksb[4], vd[4], vo[4], vsb[4];
#pragma unroll
  for (int c = 0; c < 4; ++c) {
    const int fl = c * 256 + tid;
    kr[c] = fl >> 3; ko[c] = (fl & 7) * 8;
    ksb[c] = kr[c] * 128 + ((ko[c] * 2) ^ ((kr[c] & 7) << 4));
    vd[c] = fl >> 4; vo[c] = (fl & 15) * 8;
    vsb[c] = vd[c] * 256 + ((vo[c] * 2) ^ ((vd[c] & 15) << 4));
  }
  const u16* Kbase = qkv + (size_t)b * T * C3 + C + h * D;
  const u16* Vbase = vt + (size_t)bh * D * T;
  char* lPb = (char*)lP + w * 4096;

  const float qscale = 0.125f * 1.44269504088896f;  // scale * log2(e)

#pragma unroll 1
  for (int qi = 0; qi < 2; ++qi) {
    const int qt = (qi == 0) ? pi : (NQ - 1 - pi);
    const int q0 = qt * 64;
    const int nkt = (qt + 2) >> 1;
    const int qrow = q0 + w * 16 + l15;  // this lane's global q index

    const size_t qoff = ((size_t)b * T + qrow) * C3 + h * D;
    const bf16x8 aq0 = *(const bf16x8*)&qkv[qoff + lg * 8];
    const bf16x8 aq1 = *(const bf16x8*)&qkv[qoff + 32 + lg * 8];

    float m = -1.0e30f, l = 0.f;
    f32x4 o_acc[4];
#pragma unroll
    for (int nf = 0; nf < 4; ++nf) o_acc[nf] = (f32x4){0.f, 0.f, 0.f, 0.f};

    u32x4 rk[4], rv[4];
#pragma unroll
    for (int c = 0; c < 4; ++c) {
      rk[c] = *(const u32x4*)(Kbase + (size_t)kr[c] * C3 + ko[c]);
      rv[c] = *(const u32x4*)(Vbase + (size_t)vd[c] * T + vo[c]);
    }
    __syncthreads();  // prev pass readers drained
#pragma unroll
    for (int c = 0; c < 4; ++c) {
      *(u32x4*)((char*)lK[0] + ksb[c]) = rk[c];
      *(u32x4*)((char*)lV[0] + vsb[c]) = rv[c];
    }
    if (nkt > 1) {
#pragma unroll
      for (int c = 0; c < 4; ++c) {
        rk[c] = *(const u32x4*)(Kbase + (size_t)(KB + kr[c]) * C3 + ko[c]);
        rv[c] = *(const u32x4*)(Vbase + (size_t)vd[c] * T + KB + vo[c]);
      }
    }

    for (int kt = 0; kt < nkt; ++kt) {
      const int cur = kt & 1;
      __syncthreads();  // buf[cur] visible; buf[cur^1] readers drained
      if (kt < nkt - 1) {
#pragma unroll
        for (int c = 0; c < 4; ++c) {
          *(u32x4*)((char*)lK[cur ^ 1] + ksb[c]) = rk[c];
          *(u32x4*)((char*)lV[cur ^ 1] + vsb[c]) = rv[c];
        }
        if (kt + 1 < nkt - 1) {
          const int kn = (kt + 2) * KB;
#pragma unroll
          for (int c = 0; c < 4; ++c) {
            rk[c] = *(const u32x4*)(Kbase + (size_t)(kn + kr[c]) * C3 + ko[c]);
            rv[c] = *(const u32x4*)(Vbase + (size_t)vd[c] * T + kn + vo[c]);
          }
        }
      }
      const char* Kc = (const char*)lK[cur];
      const char* Vc = (const char*)lV[cur];

      // S^T = K Q^T: 8 kv-fragments x 2 d-halves = 16 MFMA
      f32x4 s[8];
#pragma unroll
      for (int nf = 0; nf < 8; ++nf) s[nf] = (f32x4){0.f, 0.f, 0.f, 0.f};
      __builtin_amdgcn_s_setprio(1);
#pragma unroll
      for (int nf = 0; nf < 8; ++nf) {
        const int row = nf * 16 + l15;
        const int x = (row & 7) << 4;
        bf16x8 bk0 = *(const bf16x8*)(Kc + row * 128 + ((lg * 16) ^ x));
        bf16x8 bk1 = *(const bf16x8*)(Kc + row * 128 + ((64 + lg * 16) ^ x));
        s[nf] = __builtin_amdgcn_mfma_f32_16x16x32_bf16(bk0, aq0, s[nf], 0, 0, 0);
        s[nf] = __builtin_amdgcn_mfma_f32_16x16x32_bf16(bk1, aq1, s[nf], 0, 0, 0);
      }
      __builtin_amdgcn_s_setprio(0);

      // scale (+ causal mask on last tile only)
      if (kt == nkt - 1) {
        const int qrel = qrow - kt * KB;
#pragma unroll
        for (int nf = 0; nf < 8; ++nf)
#pragma unroll
          for (int r = 0; r < 4; ++r) {
            float v = s[nf][r] * qscale;
            if (nf * 16 + lg * 4 + r > qrel) v = -1.0e30f;
            s[nf][r] = v;
          }
      } else {
#pragma unroll
        for (int nf = 0; nf < 8; ++nf)
#pragma unroll
          for (int r = 0; r < 4; ++r) s[nf][r] *= qscale;
      }

      // row max: in-register tree (31) + 2 shfl_xor
      float q4[8];
#pragma unroll
      for (int nf = 0; nf < 8; ++nf)
        q4[nf] = fmaxf(fmaxf(s[nf][0], s[nf][1]), fmaxf(s[nf][2], s[nf][3]));
      float pmax = fmaxf(fmaxf(fmaxf(q4[0], q4[1]), fmaxf(q4[2], q4[3])),
                         fmaxf(fmaxf(q4[4], q4[5]), fmaxf(q4[6], q4[7])));
      pmax = fmaxf(pmax, __shfl_xor(pmax, 16));
      pmax = fmaxf(pmax, __shfl_xor(pmax, 32));

      // defer-max (THR=0, exact)
      if (!__all(pmax <= m)) {
        const float mnew = fmaxf(m, pmax);
        const float fct = __builtin_amdgcn_exp2f(m - mnew);
        m = mnew;
        l *= fct;
#pragma unroll
        for (int r = 0; r < 4; ++r) {
          const float fr = __shfl(fct, lg * 4 + r);
#pragma unroll
          for (int nf = 0; nf < 4; ++nf) o_acc[nf][r] *= fr;
        }
      }

      // P = exp2(S - m); sum tree + 2 shfl_xor
#pragma unroll
      for (int nf = 0; nf < 8; ++nf)
#pragma unroll
        for (int r = 0; r < 4; ++r) s[nf][r] = __builtin_amdgcn_exp2f(s[nf][r] - m);
      float a4[8];
#pragma unroll
      for (int nf = 0; nf < 8; ++nf)
        a4[nf] = (s[nf][0] + s[nf][1]) + (s[nf][2] + s[nf][3]);
      float psum = ((a4[0] + a4[1]) + (a4[2] + a4[3])) + ((a4[4] + a4[5]) + (a4[6] + a4[7]));
      psum += __shfl_xor(psum, 16);
      psum += __shfl_xor(psum, 32);
      l += psum;

      // P -> per-wave LDS (packed u16x4 per nf), swz (q&15)<<4; same-wave RAW
#pragma unroll
      for (int nf = 0; nf < 8; ++nf) {
        u16x4 pk;
        pk[0] = f2bf(s[nf][0]); pk[1] = f2bf(s[nf][1]);
        pk[2] = f2bf(s[nf][2]); pk[3] = f2bf(s[nf][3]);
        *(u16x4*)(lPb + l15 * 256 + ((nf * 32 + lg * 8) ^ (l15 << 4))) = pk;
      }

      // O += P V: 4 kv-slices x 4 d-fragments = 16 MFMA
      __builtin_amdgcn_s_setprio(1);
#pragma unroll
      for (int sj = 0; sj < 4; ++sj) {
        bf16x8 ap = *(const bf16x8*)(lPb + l15 * 256 + ((sj * 64 + lg * 16) ^ (l15 << 4)));
#pragma unroll
        for (int nf = 0; nf < 4; ++nf) {
          const int d = nf * 16 + l15;
          bf16x8 bv = *(const bf16x8*)(Vc + d * 256 + ((sj * 64 + lg * 16) ^ ((d & 15) << 4)));
          o_acc[nf] = __builtin_amdgcn_mfma_f32_16x16x32_bf16(ap, bv, o_acc[nf], 0, 0, 0);
        }
      }
      __builtin_amdgcn_s_setprio(0);
    }

    // epilogue
#pragma unroll
    for (int r = 0; r < 4; ++r) {
      const float li = __builtin_amdgcn_rcpf(__shfl(l, lg * 4 + r));
      const int row = q0 + w * 16 + lg * 4 + r;
#pragma unroll
      for (int nf = 0; nf < 4; ++nf) {
        const int col = h * D + nf * 16 + l15;
        y[((size_t)b * T + row) * C + col] = f2bf(o_acc[nf][r] * li);
      }
    }
  }
}

extern "C" void kernel_launch(void* const* d_in, const int* in_sizes, int n_in,
                              void* d_out, int out_size, void* d_ws, size_t ws_size,
                              hipStream_t stream) {
  const float* x = (const float*)d_in[0];
  const float* Wqkv = (const float*)d_in[1];
  const float* Wproj = (const float*)d_in[2];
  float* out = (float*)d_out;

  constexpr int B = 2, T = 2048, C = 1024, C3 = 3072, H = 16, D = 64;
  constexpr int M = B * T;  // 4096

  u16* xb = (u16*)d_ws;                       // M*C
  u16* wqkvb = xb + (size_t)M * C;            // C3*C
  u16* wprojb = wqkvb + (size_t)C3 * C;       // C*C
  u16* qkvb = wprojb + (size_t)C * C;         // M*C3 (v-part unused)
  u16* vtb = qkvb + (size_t)M * C3;           // B*H*D*T = M*C
  u16* yb = vtb + (size_t)M * C;              // M*C

  constexpr int n1 = (M * C) / 4, n2 = (C3 * C) / 4, n3 = (C * C) / 4;
  cvt3_f32_bf16<<<dim3((n1 + n2 + n3 + 255) / 256), 256, 0, stream>>>(
      x, Wqkv, Wproj, xb, n1, n2, n3);

  gemm_nt<1, 1><<<dim3((C3 / 128) * (M / 128)), 256, 0, stream>>>(
      xb, wqkvb, qkvb, vtb, M, C3, C, M / 128);
  attn_fwd<<<dim3(512), 256, 0, stream>>>(qkvb, vtb, yb);
  gemm_nt<0, 0><<<dim3((C / 128) * (M / 128)), 256, 0, stream>>>(
      yb, wprojb, out, nullptr, M, C, C, M / 128);
}

// Round 11
// 123.528 us; speedup vs baseline: 1.0475x; 1.0475x over previous
//
#include <hip/hip_runtime.h>

typedef unsigned short u16;
typedef float f32x4 __attribute__((ext_vector_type(4)));
typedef __bf16 bf16x8 __attribute__((ext_vector_type(8)));
typedef unsigned int u32x4 __attribute__((ext_vector_type(4)));
typedef u16 u16x4 __attribute__((ext_vector_type(4)));
typedef u16 u16x8 __attribute__((ext_vector_type(8)));

static __device__ __forceinline__ u16 f2bf(float f) {
  union { __bf16 h; u16 u; } c;
  c.h = (__bf16)f;
  return c.u;
}
static __device__ __forceinline__ float bf2f(u16 u) {
  union { unsigned u; float f; } c;
  c.u = ((unsigned)u) << 16;
  return c.f;
}

static __device__ __forceinline__ void gload_lds16(const void* g, void* l) {
  __builtin_amdgcn_global_load_lds(
      (const __attribute__((address_space(1))) unsigned int*)g,
      (__attribute__((address_space(3))) unsigned int*)l, 16, 0, 0);
}

// ---------------- fused fp32 -> bf16 convert (x, Wqkv, Wproj in one launch) ----------------
__global__ __launch_bounds__(256) void cvt3_f32_bf16(const float* __restrict__ a,
                                                     const float* __restrict__ bb,
                                                     const float* __restrict__ cc,
                                                     u16* __restrict__ out,
                                                     int n1, int n2, int n3) {
  int i = blockIdx.x * 256 + threadIdx.x;
  const float* src;
  int j = i;
  if (i < n1) { src = a; }
  else if (i < n1 + n2) { src = bb; j = i - n1; }
  else { src = cc; j = i - n1 - n2; if (j >= n3) return; }
  f32x4 v = *((const f32x4*)src + j);
  u16x4 o;
  o[0] = f2bf(v[0]); o[1] = f2bf(v[1]); o[2] = f2bf(v[2]); o[3] = f2bf(v[3]);
  *((u16x4*)out + i) = o;
}

// ---------------- GEMM: C[M,N] = A[M,K] * B[N,K]^T (bf16 in, fp32 acc) ----------------
// 128x128 tile, BK=64, 4 waves. global_load_lds w16 staging, both-sides swizzle.
// XCD-aware 1D decode. FUSE_VT: v-panels (bn>=2048) write vt[bh][d][t] directly.
template<int OUT_BF16, int FUSE_VT>
__global__ __launch_bounds__(256) void gemm_nt(const u16* __restrict__ A,
                                               const u16* __restrict__ B,
                                               void* __restrict__ Cp,
                                               u16* __restrict__ vt,
                                               int M, int N, int K, int gy) {
  __shared__ __align__(16) u16 lA[128 * 64];
  __shared__ __align__(16) u16 lB[128 * 64];
  const int tid = threadIdx.x;
  const int lane = tid & 63;
  const int wave = tid >> 6;
  const int wm = wave >> 1, wn = wave & 1;
  const int l15 = lane & 15, lg = lane >> 4;

  const int bid = blockIdx.x;
  const int xcd = bid & 7, s = bid >> 3;
  const int pnx = (N >> 7) >> 3;            // B-panels per XCD
  const int bm = (s % gy) * 128;
  const int bn = (xcd * pnx + s / gy) * 128;

  f32x4 acc[4][4];
#pragma unroll
  for (int i = 0; i < 4; ++i)
#pragma unroll
    for (int j = 0; j < 4; ++j) acc[i][j] = (f32x4){0.f, 0.f, 0.f, 0.f};

  const u16* Ag[4];
  const u16* Bg[4];
#pragma unroll
  for (int it = 0; it < 4; ++it) {
    const int ss = it * 256 + tid;
    const int row = ss >> 3, g = ss & 7;
    const int gsw = g ^ (row & 7);  // inverse swizzle on global source
    Ag[it] = A + (size_t)(bm + row) * K + gsw * 8;
    Bg[it] = B + (size_t)(bn + row) * K + gsw * 8;
  }

  for (int k0 = 0; k0 < K; k0 += 64) {
#pragma unroll
    for (int it = 0; it < 4; ++it) {
      gload_lds16(Ag[it] + k0, (u16*)lA + (size_t)(it * 256 + tid) * 8);
      gload_lds16(Bg[it] + k0, (u16*)lB + (size_t)(it * 256 + tid) * 8);
    }
    __syncthreads();
#pragma unroll
    for (int kk = 0; kk < 2; ++kk) {
      bf16x8 af[4], bfv[4];
#pragma unroll
      for (int mf = 0; mf < 4; ++mf) {
        const int row = wm * 64 + mf * 16 + l15;
        af[mf] = *(const bf16x8*)((const char*)lA + row * 128 +
                                  ((kk * 64 + lg * 16) ^ ((row & 7) << 4)));
      }
#pragma unroll
      for (int nf = 0; nf < 4; ++nf) {
        const int row = wn * 64 + nf * 16 + l15;
        bfv[nf] = *(const bf16x8*)((const char*)lB + row * 128 +
                                   ((kk * 64 + lg * 16) ^ ((row & 7) << 4)));
      }
#pragma unroll
      for (int mf = 0; mf < 4; ++mf)
#pragma unroll
        for (int nf = 0; nf < 4; ++nf)
          acc[mf][nf] = __builtin_amdgcn_mfma_f32_16x16x32_bf16(af[mf], bfv[nf], acc[mf][nf], 0, 0, 0);
    }
    __syncthreads();
  }

  if (FUSE_VT && bn >= 2048) {
#pragma unroll
    for (int mf = 0; mf < 4; ++mf) {
      const int row0 = bm + wm * 64 + mf * 16 + lg * 4;
      const int b = row0 >> 11, t0 = row0 & 2047;
#pragma unroll
      for (int nf = 0; nf < 4; ++nf) {
        const int colv = bn - 2048 + wn * 64 + nf * 16 + l15;
        const int h = colv >> 6, d = colv & 63;
        u16x4 pk;
        pk[0] = f2bf(acc[mf][nf][0]); pk[1] = f2bf(acc[mf][nf][1]);
        pk[2] = f2bf(acc[mf][nf][2]); pk[3] = f2bf(acc[mf][nf][3]);
        *(u16x4*)&vt[((size_t)((b * 16 + h) * 64 + d)) * 2048 + t0] = pk;
      }
    }
  } else {
#pragma unroll
    for (int mf = 0; mf < 4; ++mf) {
#pragma unroll
      for (int r = 0; r < 4; ++r) {
        const int row = bm + wm * 64 + mf * 16 + lg * 4 + r;
#pragma unroll
        for (int nf = 0; nf < 4; ++nf) {
          const int col = bn + wn * 64 + nf * 16 + l15;
          const float v = acc[mf][nf][r];
          if (OUT_BF16) ((u16*)Cp)[(size_t)row * N + col] = f2bf(v);
          else          ((float*)Cp)[(size_t)row * N + col] = v;
        }
      }
    }
  }
}

// ---------------- flash attention fwd (causal), kv-split halves ----------------
// R7 body (KVBLK=64, 40KB LDS, swapped QK^T, THR=0 defer-max, dbuf, 2-deep
// prefetch). Block (pi,hf) does half hf of q-tiles pi and 31-pi: 17 (hf=0) or
// 16 (hf=1) iters for every pi -> uniform. Grid 1024 = 4 blocks/CU.
// Writes l-normalized bf16 partial O + (m,l); merge_o combines halves.
__global__ __launch_bounds__(256) void attn_fwd(const u16* __restrict__ qkv,
                                                const u16* __restrict__ vt,
                                                u16* __restrict__ po,
                                                float* __restrict__ mlf) {
  constexpr int T = 2048, C = 1024, C3 = 3072, D = 64, NQ = 32;
  __shared__ __align__(16) u16 lK[2][64 * 64];
  __shared__ __align__(16) u16 lV[2][64 * 64];
  __shared__ __align__(16) u16 lP[4 * 16 * 64];
  const int tid = threadIdx.x, lane = tid & 63, w = tid >> 6;
  const int l15 = lane & 15, lg = lane >> 4;

  // decode: XCD-local bh, pair index pi, kv-half hf
  const int bid = blockIdx.x;
  const int xcd = bid & 7, rest = bid >> 3;
  const int bhl = rest >> 5, r5 = rest & 31;
  const int pi = r5 >> 1, hf = r5 & 1;
  const int bh = xcd * 4 + bhl;
  const int b = bh >> 4, h = bh & 15;

  const int r0 = tid >> 3, off0 = (tid & 7) * 8;
  const int r1 = (tid + 256) >> 3;
  const int sb0 = (off0 * 2) ^ ((r0 & 7) << 4);
  const int sb1 = (off0 * 2) ^ ((r1 & 7) << 4);
  const u16* Kbase = qkv + (size_t)b * T * C3 + C + h * D;
  const u16* Vbase = vt + (size_t)bh * D * T;

  const float qscale = 0.125f * 1.44269504088896f;  // scale * log2(e)

#pragma unroll 1
  for (int qi = 0; qi < 2; ++qi) {
    const int qt = (qi == 0) ? pi : (NQ - 1 - pi);
    const int q0 = qt * 64;
    const int h0 = (qt + 2) >> 1;            // ceil((qt+1)/2)
    const int kts = hf ? h0 : 0;
    const int kte = hf ? (qt + 1) : h0;
    const int nit = kte - kts;

    const size_t qoff = ((size_t)b * T + q0 + w * 16 + l15) * C3 + h * D;
    const bf16x8 aq0 = *(const bf16x8*)&qkv[qoff + lg * 8];
    const bf16x8 aq1 = *(const bf16x8*)&qkv[qoff + 32 + lg * 8];

    float m = -1.0e30f, l = 0.f;   // per-lane: q-row = w*16 + l15
    f32x4 o_acc[4];
#pragma unroll
    for (int nf = 0; nf < 4; ++nf) o_acc[nf] = (f32x4){0.f, 0.f, 0.f, 0.f};

    if (nit > 0) {
      const int kb0 = kts * 64;
      u32x4 rk0 = *(const u32x4*)(Kbase + (size_t)(kb0 + r0) * C3 + off0);
      u32x4 rk1 = *(const u32x4*)(Kbase + (size_t)(kb0 + r1) * C3 + off0);
      u32x4 rv0 = *(const u32x4*)(Vbase + (size_t)r0 * T + kb0 + off0);
      u32x4 rv1 = *(const u32x4*)(Vbase + (size_t)r1 * T + kb0 + off0);
      __syncthreads();  // prev pass readers drained
      *(u32x4*)&lK[0][(r0 * 128 + sb0) >> 1] = rk0;
      *(u32x4*)&lK[0][(r1 * 128 + sb1) >> 1] = rk1;
      *(u32x4*)&lV[0][(r0 * 128 + sb0) >> 1] = rv0;
      *(u32x4*)&lV[0][(r1 * 128 + sb1) >> 1] = rv1;
      if (nit > 1) {
        const int kb1 = kb0 + 64;
        rk0 = *(const u32x4*)(Kbase + (size_t)(kb1 + r0) * C3 + off0);
        rk1 = *(const u32x4*)(Kbase + (size_t)(kb1 + r1) * C3 + off0);
        rv0 = *(const u32x4*)(Vbase + (size_t)r0 * T + kb1 + off0);
        rv1 = *(const u32x4*)(Vbase + (size_t)r1 * T + kb1 + off0);
      }

      for (int i = 0; i < nit; ++i) {
        const int kt = kts + i;
        const int cur = i & 1;
        __syncthreads();  // buf[cur] visible; buf[cur^1] readers drained
        if (i < nit - 1) {
          *(u32x4*)&lK[cur ^ 1][(r0 * 128 + sb0) >> 1] = rk0;
          *(u32x4*)&lK[cur ^ 1][(r1 * 128 + sb1) >> 1] = rk1;
          *(u32x4*)&lV[cur ^ 1][(r0 * 128 + sb0) >> 1] = rv0;
          *(u32x4*)&lV[cur ^ 1][(r1 * 128 + sb1) >> 1] = rv1;
          if (i + 1 < nit - 1) {
            const int kn = (kt + 2) * 64;
            rk0 = *(const u32x4*)(Kbase + (size_t)(kn + r0) * C3 + off0);
            rk1 = *(const u32x4*)(Kbase + (size_t)(kn + r1) * C3 + off0);
            rv0 = *(const u32x4*)(Vbase + (size_t)r0 * T + kn + off0);
            rv1 = *(const u32x4*)(Vbase + (size_t)r1 * T + kn + off0);
          }
        }
        const u16* Kc = lK[cur];
        const u16* Vc = lV[cur];

        f32x4 s[4];
#pragma unroll
        for (int nf = 0; nf < 4; ++nf) s[nf] = (f32x4){0.f, 0.f, 0.f, 0.f};
        __builtin_amdgcn_s_setprio(1);
#pragma unroll
        for (int nf = 0; nf < 4; ++nf) {
          const int row = nf * 16 + l15;
          const int x = (row & 7) << 4;
          bf16x8 bk0 = *(const bf16x8*)&Kc[(row * 128 + ((lg * 16) ^ x)) >> 1];
          bf16x8 bk1 = *(const bf16x8*)&Kc[(row * 128 + ((64 + lg * 16) ^ x)) >> 1];
          s[nf] = __builtin_amdgcn_mfma_f32_16x16x32_bf16(bk0, aq0, s[nf], 0, 0, 0);
          s[nf] = __builtin_amdgcn_mfma_f32_16x16x32_bf16(bk1, aq1, s[nf], 0, 0, 0);
        }
        __builtin_amdgcn_s_setprio(0);

#pragma unroll
        for (int nf = 0; nf < 4; ++nf) {
#pragma unroll
          for (int r = 0; r < 4; ++r) {
            float v = s[nf][r] * qscale;
            if (kt == qt) {
              if (nf * 16 + lg * 4 + r > w * 16 + l15) v = -1.0e30f;
            }
            s[nf][r] = v;
          }
        }

        float t0a = fmaxf(fmaxf(s[0][0], s[0][1]), fmaxf(s[0][2], s[0][3]));
        float t1a = fmaxf(fmaxf(s[1][0], s[1][1]), fmaxf(s[1][2], s[1][3]));
        float t2a = fmaxf(fmaxf(s[2][0], s[2][1]), fmaxf(s[2][2], s[2][3]));
        float t3a = fmaxf(fmaxf(s[3][0], s[3][1]), fmaxf(s[3][2], s[3][3]));
        float pmax = fmaxf(fmaxf(t0a, t1a), fmaxf(t2a, t3a));
        pmax = fmaxf(pmax, __shfl_xor(pmax, 16));
        pmax = fmaxf(pmax, __shfl_xor(pmax, 32));

        if (!__all(pmax <= m)) {
          const float mnew = fmaxf(m, pmax);
          const float fct = __builtin_amdgcn_exp2f(m - mnew);
          m = mnew;
          l *= fct;
#pragma unroll
          for (int r = 0; r < 4; ++r) {
            const float fr = __shfl(fct, lg * 4 + r);
#pragma unroll
            for (int nf = 0; nf < 4; ++nf) o_acc[nf][r] *= fr;
          }
        }

        float p[4][4];
#pragma unroll
        for (int nf = 0; nf < 4; ++nf)
#pragma unroll
          for (int r = 0; r < 4; ++r) p[nf][r] = __builtin_amdgcn_exp2f(s[nf][r] - m);
        float s0a = (p[0][0] + p[0][1]) + (p[0][2] + p[0][3]);
        float s1a = (p[1][0] + p[1][1]) + (p[1][2] + p[1][3]);
        float s2a = (p[2][0] + p[2][1]) + (p[2][2] + p[2][3]);
        float s3a = (p[3][0] + p[3][1]) + (p[3][2] + p[3][3]);
        float psum = (s0a + s1a) + (s2a + s3a);
        psum += __shfl_xor(psum, 16);
        psum += __shfl_xor(psum, 32);
        l += psum;

#pragma unroll
        for (int nf = 0; nf < 4; ++nf) {
          u16x4 pk;
          pk[0] = f2bf(p[nf][0]); pk[1] = f2bf(p[nf][1]);
          pk[2] = f2bf(p[nf][2]); pk[3] = f2bf(p[nf][3]);
          *(u16x4*)&lP[(w * 2048 + l15 * 128 + ((nf * 32 + lg * 8) ^ ((l15 & 7) << 4))) >> 1] = pk;
        }

        __builtin_amdgcn_s_setprio(1);
#pragma unroll
        for (int sj = 0; sj < 2; ++sj) {
          bf16x8 ap = *(const bf16x8*)&lP[(w * 2048 + l15 * 128 + ((sj * 64 + lg * 16) ^ ((l15 & 7) << 4))) >> 1];
#pragma unroll
          for (int nf = 0; nf < 4; ++nf) {
            const int d = nf * 16 + l15;
            bf16x8 bv = *(const bf16x8*)&Vc[(d * 128 + ((sj * 64 + lg * 16) ^ ((d & 7) << 4))) >> 1];
            o_acc[nf] = __builtin_amdgcn_mfma_f32_16x16x32_bf16(ap, bv, o_acc[nf], 0, 0, 0);
          }
        }
        __builtin_amdgcn_s_setprio(0);
      }
    }

    // epilogue: l-normalized partial O (bf16) + (m,l) per q-row
    u16* pob = po + (size_t)hf * (4096ull * 1024ull);
#pragma unroll
    for (int r = 0; r < 4; ++r) {
      const float lv = __shfl(l, lg * 4 + r);
      const float li = (lv > 0.f) ? __builtin_amdgcn_rcpf(lv) : 0.f;
      const int row = q0 + w * 16 + lg * 4 + r;
#pragma unroll
      for (int nf = 0; nf < 4; ++nf) {
        const int col = h * D + nf * 16 + l15;
        pob[((size_t)b * T + row) * C + col] = f2bf(o_acc[nf][r] * li);
      }
    }
    if (lg == 0) {
      const size_t idx = (size_t)(b * T + q0 + w * 16 + l15) * 16 + h;
      float* mp = mlf + (size_t)hf * 131072ull + idx * 2;
      mp[0] = m;
      mp[1] = l;
    }
  }
}

// ---------------- merge the two kv-halves: y = w1*o1 + w2*o2 ----------------
__global__ __launch_bounds__(256) void merge_o(const u16* __restrict__ po,
                                               const float* __restrict__ mlf,
                                               u16* __restrict__ y) {
  const int gid = blockIdx.x * 256 + threadIdx.x;   // 524288 threads
  const int row = gid >> 3, d0 = (gid & 7) * 8;     // row in [0, 65536)
  const int bt = row >> 4, h = row & 15;
  const float m1 = mlf[row * 2], l1 = mlf[row * 2 + 1];
  const float m2 = mlf[131072 + row * 2], l2 = mlf[131072 + row * 2 + 1];
  const float ms = fmaxf(m1, m2);
  const float a1 = l1 * __builtin_amdgcn_exp2f(m1 - ms);
  const float a2 = l2 * __builtin_amdgcn_exp2f(m2 - ms);
  const float inv = __builtin_amdgcn_rcpf(a1 + a2);
  const float w1 = a1 * inv, w2 = a2 * inv;
  const size_t off = (size_t)bt * 1024 + h * 64 + d0;
  u16x8 p1 = *(const u16x8*)&po[off];
  u16x8 p2 = *(const u16x8*)&po[4194304ull + off];
  u16x8 o;
#pragma unroll
  for (int j = 0; j < 8; ++j) o[j] = f2bf(w1 * bf2f(p1[j]) + w2 * bf2f(p2[j]));
  *(u16x8*)&y[off] = o;
}

extern "C" void kernel_launch(void* const* d_in, const int* in_sizes, int n_in,
                              void* d_out, int out_size, void* d_ws, size_t ws_size,
                              hipStream_t stream) {
  const float* x = (const float*)d_in[0];
  const float* Wqkv = (const float*)d_in[1];
  const float* Wproj = (const float*)d_in[2];
  float* out = (float*)d_out;

  constexpr int B = 2, T = 2048, C = 1024, C3 = 3072, H = 16, D = 64;
  constexpr int M = B * T;  // 4096

  u16* xb = (u16*)d_ws;                       // M*C
  u16* wqkvb = xb + (size_t)M * C;            // C3*C
  u16* wprojb = wqkvb + (size_t)C3 * C;       // C*C
  u16* qkvb = wprojb + (size_t)C * C;         // M*C3 (v-part unused)
  u16* vtb = qkvb + (size_t)M * C3;           // B*H*D*T = M*C
  u16* yb = vtb + (size_t)M * C;              // M*C
  u16* po = yb + (size_t)M * C;               // 2 * M*C (both halves)
  float* mlf = (float*)(po + 2ull * M * C);   // 2 * 65536 * 2 floats

  constexpr int n1 = (M * C) / 4, n2 = (C3 * C) / 4, n3 = (C * C) / 4;
  cvt3_f32_bf16<<<dim3((n1 + n2 + n3 + 255) / 256), 256, 0, stream>>>(
      x, Wqkv, Wproj, xb, n1, n2, n3);

  gemm_nt<1, 1><<<dim3((C3 / 128) * (M / 128)), 256, 0, stream>>>(
      xb, wqkvb, qkvb, vtb, M, C3, C, M / 128);
  attn_fwd<<<dim3(1024), 256, 0, stream>>>(qkvb, vtb, po, mlf);
  merge_o<<<dim3(2048), 256, 0, stream>>>(po, mlf, yb);
  gemm_nt<0, 0><<<dim3((C / 128) * (M / 128)), 256, 0, stream>>>(
      yb, wprojb, out, nullptr, M, C, C, M / 128);
}

// Round 12
// 114.457 us; speedup vs baseline: 1.1305x; 1.0793x over previous
//
#include <hip/hip_runtime.h>

typedef unsigned short u16;
typedef float f32x4 __attribute__((ext_vector_type(4)));
typedef __bf16 bf16x8 __attribute__((ext_vector_type(8)));
typedef unsigned int u32x4 __attribute__((ext_vector_type(4)));
typedef u16 u16x4 __attribute__((ext_vector_type(4)));
typedef u16 u16x8 __attribute__((ext_vector_type(8)));

static __device__ __forceinline__ u16 f2bf(float f) {
  union { __bf16 h; u16 u; } c;
  c.h = (__bf16)f;
  return c.u;
}

static __device__ __forceinline__ void gload_lds16(const void* g, void* l) {
  __builtin_amdgcn_global_load_lds(
      (const __attribute__((address_space(1))) unsigned int*)g,
      (__attribute__((address_space(3))) unsigned int*)l, 16, 0, 0);
}

// ---------------- fused fp32 -> bf16 convert (x, Wqkv, Wproj in one launch) ----------------
__global__ __launch_bounds__(256) void cvt3_f32_bf16(const float* __restrict__ a,
                                                     const float* __restrict__ bb,
                                                     const float* __restrict__ cc,
                                                     u16* __restrict__ out,
                                                     int n1, int n2, int n3) {
  int i = blockIdx.x * 256 + threadIdx.x;
  const float* src;
  int j = i;
  if (i < n1) { src = a; }
  else if (i < n1 + n2) { src = bb; j = i - n1; }
  else { src = cc; j = i - n1 - n2; if (j >= n3) return; }
  f32x4 v = *((const f32x4*)src + j);
  u16x4 o;
  o[0] = f2bf(v[0]); o[1] = f2bf(v[1]); o[2] = f2bf(v[2]); o[3] = f2bf(v[3]);
  *((u16x4*)out + i) = o;
}

// ---------------- GEMM: C[M,N] = A[M,K] * B[N,K]^T (bf16 in, fp32 acc) ----------------
// 128x128 tile, BK=64, 4 waves. global_load_lds w16 staging, both-sides swizzle.
// XCD-aware 1D decode. FUSE_VT: v-panels (bn>=2048) write vt[bh][d][t] directly.
template<int OUT_BF16, int FUSE_VT>
__global__ __launch_bounds__(256) void gemm_nt(const u16* __restrict__ A,
                                               const u16* __restrict__ B,
                                               void* __restrict__ Cp,
                                               u16* __restrict__ vt,
                                               int M, int N, int K, int gy) {
  __shared__ __align__(16) u16 lA[128 * 64];
  __shared__ __align__(16) u16 lB[128 * 64];
  const int tid = threadIdx.x;
  const int lane = tid & 63;
  const int wave = tid >> 6;
  const int wm = wave >> 1, wn = wave & 1;
  const int l15 = lane & 15, lg = lane >> 4;

  const int bid = blockIdx.x;
  const int xcd = bid & 7, s = bid >> 3;
  const int pnx = (N >> 7) >> 3;            // B-panels per XCD
  const int bm = (s % gy) * 128;
  const int bn = (xcd * pnx + s / gy) * 128;

  f32x4 acc[4][4];
#pragma unroll
  for (int i = 0; i < 4; ++i)
#pragma unroll
    for (int j = 0; j < 4; ++j) acc[i][j] = (f32x4){0.f, 0.f, 0.f, 0.f};

  const u16* Ag[4];
  const u16* Bg[4];
#pragma unroll
  for (int it = 0; it < 4; ++it) {
    const int ss = it * 256 + tid;
    const int row = ss >> 3, g = ss & 7;
    const int gsw = g ^ (row & 7);  // inverse swizzle on global source
    Ag[it] = A + (size_t)(bm + row) * K + gsw * 8;
    Bg[it] = B + (size_t)(bn + row) * K + gsw * 8;
  }

  for (int k0 = 0; k0 < K; k0 += 64) {
#pragma unroll
    for (int it = 0; it < 4; ++it) {
      gload_lds16(Ag[it] + k0, (u16*)lA + (size_t)(it * 256 + tid) * 8);
      gload_lds16(Bg[it] + k0, (u16*)lB + (size_t)(it * 256 + tid) * 8);
    }
    __syncthreads();
#pragma unroll
    for (int kk = 0; kk < 2; ++kk) {
      bf16x8 af[4], bfv[4];
#pragma unroll
      for (int mf = 0; mf < 4; ++mf) {
        const int row = wm * 64 + mf * 16 + l15;
        af[mf] = *(const bf16x8*)((const char*)lA + row * 128 +
                                  ((kk * 64 + lg * 16) ^ ((row & 7) << 4)));
      }
#pragma unroll
      for (int nf = 0; nf < 4; ++nf) {
        const int row = wn * 64 + nf * 16 + l15;
        bfv[nf] = *(const bf16x8*)((const char*)lB + row * 128 +
                                   ((kk * 64 + lg * 16) ^ ((row & 7) << 4)));
      }
#pragma unroll
      for (int mf = 0; mf < 4; ++mf)
#pragma unroll
        for (int nf = 0; nf < 4; ++nf)
          acc[mf][nf] = __builtin_amdgcn_mfma_f32_16x16x32_bf16(af[mf], bfv[nf], acc[mf][nf], 0, 0, 0);
    }
    __syncthreads();
  }

  if (FUSE_VT && bn >= 2048) {
#pragma unroll
    for (int mf = 0; mf < 4; ++mf) {
      const int row0 = bm + wm * 64 + mf * 16 + lg * 4;
      const int b = row0 >> 11, t0 = row0 & 2047;
#pragma unroll
      for (int nf = 0; nf < 4; ++nf) {
        const int colv = bn - 2048 + wn * 64 + nf * 16 + l15;
        const int h = colv >> 6, d = colv & 63;
        u16x4 pk;
        pk[0] = f2bf(acc[mf][nf][0]); pk[1] = f2bf(acc[mf][nf][1]);
        pk[2] = f2bf(acc[mf][nf][2]); pk[3] = f2bf(acc[mf][nf][3]);
        *(u16x4*)&vt[((size_t)((b * 16 + h) * 64 + d)) * 2048 + t0] = pk;
      }
    }
  } else {
#pragma unroll
    for (int mf = 0; mf < 4; ++mf) {
#pragma unroll
      for (int r = 0; r < 4; ++r) {
        const int row = bm + wm * 64 + mf * 16 + lg * 4 + r;
#pragma unroll
        for (int nf = 0; nf < 4; ++nf) {
          const int col = bn + wn * 64 + nf * 16 + l15;
          const float v = acc[mf][nf][r];
          if (OUT_BF16) ((u16*)Cp)[(size_t)row * N + col] = f2bf(v);
          else          ((float*)Cp)[(size_t)row * N + col] = v;
        }
      }
    }
  }
}

// ---------------- flash attention fwd (causal), bf16 MFMA, pipelined ----------------
// Paired q-tiles (pi, 31-pi), 512 blocks. Swapped QK^T + defer-max (R7 body).
// SOFTWARE PIPELINE: PV lags one tile -> per iter i: issue QK(i) MFMAs, issue
// PV(i-1) MFMAs (independent), then softmax(i) VALU runs while PV executes on
// the matrix pipe. V triple-buffered (PV reads V(i-1) while V(i+1) stages);
// K double-buffered. One barrier/iter + one drain iter per q-tile.
__global__ __launch_bounds__(256) void attn_fwd(const u16* __restrict__ qkv,
                                                const u16* __restrict__ vt,
                                                u16* __restrict__ y) {
  constexpr int T = 2048, C = 1024, C3 = 3072, D = 64, NQ = 32;
  __shared__ __align__(16) u16 lK[2][64 * 64];
  __shared__ __align__(16) u16 lV[3][64 * 64];
  __shared__ __align__(16) u16 lP[4 * 16 * 64];
  const int tid = threadIdx.x, lane = tid & 63, w = tid >> 6;
  const int l15 = lane & 15, lg = lane >> 4;

  const int bid = blockIdx.x;
  const int xcd = bid & 7, slot = bid >> 3;
  const int bh = xcd * 4 + (slot >> 4);
  const int pi = slot & 15;
  const int b = bh >> 4, h = bh & 15;

  const int r0 = tid >> 3, off0 = (tid & 7) * 8;
  const int r1 = (tid + 256) >> 3;
  const int sb0 = (off0 * 2) ^ ((r0 & 7) << 4);
  const int sb1 = (off0 * 2) ^ ((r1 & 7) << 4);
  const u16* Kbase = qkv + (size_t)b * T * C3 + C + h * D;
  const u16* Vbase = vt + (size_t)bh * D * T;

  const float qscale = 0.125f * 1.44269504088896f;  // scale * log2(e)

#pragma unroll 1
  for (int qi = 0; qi < 2; ++qi) {
    const int qt = (qi == 0) ? pi : (NQ - 1 - pi);
    const int q0 = qt * 64;

    const size_t qoff = ((size_t)b * T + q0 + w * 16 + l15) * C3 + h * D;
    const bf16x8 aq0 = *(const bf16x8*)&qkv[qoff + lg * 8];
    const bf16x8 aq1 = *(const bf16x8*)&qkv[qoff + 32 + lg * 8];

    float m = -1.0e30f, l = 0.f;   // per-lane: q-row = w*16 + l15
    f32x4 o_acc[4];
#pragma unroll
    for (int nf = 0; nf < 4; ++nf) o_acc[nf] = (f32x4){0.f, 0.f, 0.f, 0.f};

    // prologue: tile 0 -> regs; drain prev pass; -> K slot0 / V slot0
    u32x4 rk0 = *(const u32x4*)(Kbase + (size_t)r0 * C3 + off0);
    u32x4 rk1 = *(const u32x4*)(Kbase + (size_t)r1 * C3 + off0);
    u32x4 rv0 = *(const u32x4*)(Vbase + (size_t)r0 * T + off0);
    u32x4 rv1 = *(const u32x4*)(Vbase + (size_t)r1 * T + off0);
    __syncthreads();
    *(u32x4*)&lK[0][(r0 * 128 + sb0) >> 1] = rk0;
    *(u32x4*)&lK[0][(r1 * 128 + sb1) >> 1] = rk1;
    *(u32x4*)&lV[0][(r0 * 128 + sb0) >> 1] = rv0;
    *(u32x4*)&lV[0][(r1 * 128 + sb1) >> 1] = rv1;
    if (qt >= 1) {
      rk0 = *(const u32x4*)(Kbase + (size_t)(64 + r0) * C3 + off0);
      rk1 = *(const u32x4*)(Kbase + (size_t)(64 + r1) * C3 + off0);
      rv0 = *(const u32x4*)(Vbase + (size_t)r0 * T + 64 + off0);
      rv1 = *(const u32x4*)(Vbase + (size_t)r1 * T + 64 + off0);
    }

    int vcur = 0;  // V slot of tile i
    for (int i = 0; i <= qt + 1; ++i) {
      const int vnext = (vcur == 2) ? 0 : vcur + 1;
      const int vprev = (vcur == 0) ? 2 : vcur - 1;
      __syncthreads();  // staged tile i visible; old buffers' readers drained
      const int wr = i + 1;
      if (wr <= qt) {
        *(u32x4*)&lK[wr & 1][(r0 * 128 + sb0) >> 1] = rk0;
        *(u32x4*)&lK[wr & 1][(r1 * 128 + sb1) >> 1] = rk1;
        *(u32x4*)&lV[vnext][(r0 * 128 + sb0) >> 1] = rv0;
        *(u32x4*)&lV[vnext][(r1 * 128 + sb1) >> 1] = rv1;
        if (wr + 1 <= qt) {
          const int kn = (wr + 1) * 64;
          rk0 = *(const u32x4*)(Kbase + (size_t)(kn + r0) * C3 + off0);
          rk1 = *(const u32x4*)(Kbase + (size_t)(kn + r1) * C3 + off0);
          rv0 = *(const u32x4*)(Vbase + (size_t)r0 * T + kn + off0);
          rv1 = *(const u32x4*)(Vbase + (size_t)r1 * T + kn + off0);
        }
      }

      // ---- QK(i): issue MFMAs (results needed only after PV issue) ----
      f32x4 s[4];
      if (i <= qt) {
        const u16* Kc = lK[i & 1];
#pragma unroll
        for (int nf = 0; nf < 4; ++nf) s[nf] = (f32x4){0.f, 0.f, 0.f, 0.f};
        __builtin_amdgcn_s_setprio(1);
#pragma unroll
        for (int nf = 0; nf < 4; ++nf) {
          const int row = nf * 16 + l15;
          const int x = (row & 7) << 4;
          bf16x8 bk0 = *(const bf16x8*)&Kc[(row * 128 + ((lg * 16) ^ x)) >> 1];
          bf16x8 bk1 = *(const bf16x8*)&Kc[(row * 128 + ((64 + lg * 16) ^ x)) >> 1];
          s[nf] = __builtin_amdgcn_mfma_f32_16x16x32_bf16(bk0, aq0, s[nf], 0, 0, 0);
          s[nf] = __builtin_amdgcn_mfma_f32_16x16x32_bf16(bk1, aq1, s[nf], 0, 0, 0);
        }
        __builtin_amdgcn_s_setprio(0);
      }

      // ---- PV(i-1): issue MFMAs; overlaps softmax(i) below ----
      if (i >= 1) {
        const u16* Vc = lV[vprev];
        __builtin_amdgcn_s_setprio(1);
#pragma unroll
        for (int sj = 0; sj < 2; ++sj) {
          bf16x8 ap = *(const bf16x8*)&lP[(w * 2048 + l15 * 128 + ((sj * 64 + lg * 16) ^ ((l15 & 7) << 4))) >> 1];
#pragma unroll
          for (int nf = 0; nf < 4; ++nf) {
            const int d = nf * 16 + l15;
            bf16x8 bv = *(const bf16x8*)&Vc[(d * 128 + ((sj * 64 + lg * 16) ^ ((d & 7) << 4))) >> 1];
            o_acc[nf] = __builtin_amdgcn_mfma_f32_16x16x32_bf16(ap, bv, o_acc[nf], 0, 0, 0);
          }
        }
        __builtin_amdgcn_s_setprio(0);
      }

      // ---- softmax(i): VALU/trans, overlapping PV on the matrix pipe ----
      if (i <= qt) {
#pragma unroll
        for (int nf = 0; nf < 4; ++nf) {
#pragma unroll
          for (int r = 0; r < 4; ++r) {
            float v = s[nf][r] * qscale;
            if (i == qt) {
              if (nf * 16 + lg * 4 + r > w * 16 + l15) v = -1.0e30f;
            }
            s[nf][r] = v;
          }
        }

        float t0a = fmaxf(fmaxf(s[0][0], s[0][1]), fmaxf(s[0][2], s[0][3]));
        float t1a = fmaxf(fmaxf(s[1][0], s[1][1]), fmaxf(s[1][2], s[1][3]));
        float t2a = fmaxf(fmaxf(s[2][0], s[2][1]), fmaxf(s[2][2], s[2][3]));
        float t3a = fmaxf(fmaxf(s[3][0], s[3][1]), fmaxf(s[3][2], s[3][3]));
        float pmax = fmaxf(fmaxf(t0a, t1a), fmaxf(t2a, t3a));
        pmax = fmaxf(pmax, __shfl_xor(pmax, 16));
        pmax = fmaxf(pmax, __shfl_xor(pmax, 32));

        if (!__all(pmax <= m)) {
          const float mnew = fmaxf(m, pmax);
          const float fct = __builtin_amdgcn_exp2f(m - mnew);
          m = mnew;
          l *= fct;
#pragma unroll
          for (int r = 0; r < 4; ++r) {
            const float fr = __shfl(fct, lg * 4 + r);  // waits PV(i-1) completion
#pragma unroll
            for (int nf = 0; nf < 4; ++nf) o_acc[nf][r] *= fr;
          }
        }

        float p[4][4];
#pragma unroll
        for (int nf = 0; nf < 4; ++nf)
#pragma unroll
          for (int r = 0; r < 4; ++r) p[nf][r] = __builtin_amdgcn_exp2f(s[nf][r] - m);
        float s0a = (p[0][0] + p[0][1]) + (p[0][2] + p[0][3]);
        float s1a = (p[1][0] + p[1][1]) + (p[1][2] + p[1][3]);
        float s2a = (p[2][0] + p[2][1]) + (p[2][2] + p[2][3]);
        float s3a = (p[3][0] + p[3][1]) + (p[3][2] + p[3][3]);
        float psum = (s0a + s1a) + (s2a + s3a);
        psum += __shfl_xor(psum, 16);
        psum += __shfl_xor(psum, 32);
        l += psum;

        // P-store AFTER PV(i-1)'s lP reads (same-wave DS in-order)
#pragma unroll
        for (int nf = 0; nf < 4; ++nf) {
          u16x4 pk;
          pk[0] = f2bf(p[nf][0]); pk[1] = f2bf(p[nf][1]);
          pk[2] = f2bf(p[nf][2]); pk[3] = f2bf(p[nf][3]);
          *(u16x4*)&lP[(w * 2048 + l15 * 128 + ((nf * 32 + lg * 8) ^ ((l15 & 7) << 4))) >> 1] = pk;
        }
      }

      vcur = vnext;
    }

    // epilogue
#pragma unroll
    for (int r = 0; r < 4; ++r) {
      const float li = __builtin_amdgcn_rcpf(__shfl(l, lg * 4 + r));
      const int row = q0 + w * 16 + lg * 4 + r;
#pragma unroll
      for (int nf = 0; nf < 4; ++nf) {
        const int col = h * D + nf * 16 + l15;
        y[((size_t)b * T + row) * C + col] = f2bf(o_acc[nf][r] * li);
      }
    }
  }
}

extern "C" void kernel_launch(void* const* d_in, const int* in_sizes, int n_in,
                              void* d_out, int out_size, void* d_ws, size_t ws_size,
                              hipStream_t stream) {
  const float* x = (const float*)d_in[0];
  const float* Wqkv = (const float*)d_in[1];
  const float* Wproj = (const float*)d_in[2];
  float* out = (float*)d_out;

  constexpr int B = 2, T = 2048, C = 1024, C3 = 3072, H = 16, D = 64;
  constexpr int M = B * T;  // 4096

  u16* xb = (u16*)d_ws;                       // M*C
  u16* wqkvb = xb + (size_t)M * C;            // C3*C
  u16* wprojb = wqkvb + (size_t)C3 * C;       // C*C
  u16* qkvb = wprojb + (size_t)C * C;         // M*C3 (v-part unused)
  u16* vtb = qkvb + (size_t)M * C3;           // B*H*D*T = M*C
  u16* yb = vtb + (size_t)M * C;              // M*C

  constexpr int n1 = (M * C) / 4, n2 = (C3 * C) / 4, n3 = (C * C) / 4;
  cvt3_f32_bf16<<<dim3((n1 + n2 + n3 + 255) / 256), 256, 0, stream>>>(
      x, Wqkv, Wproj, xb, n1, n2, n3);

  gemm_nt<1, 1><<<dim3((C3 / 128) * (M / 128)), 256, 0, stream>>>(
      xb, wqkvb, qkvb, vtb, M, C3, C, M / 128);
  attn_fwd<<<dim3(512), 256, 0, stream>>>(qkvb, vtb, yb);
  gemm_nt<0, 0><<<dim3((C / 128) * (M / 128)), 256, 0, stream>>>(
      yb, wprojb, out, nullptr, M, C, C, M / 128);
}